// Round 3
// baseline (224.693 us; speedup 1.0000x reference)
//
#include <hip/hip_runtime.h>
#include <stdint.h>

typedef unsigned short u16;
typedef unsigned int   u32;
typedef __bf16 bf16;
typedef bf16  bf16x8 __attribute__((ext_vector_type(8)));
typedef float f32x4  __attribute__((ext_vector_type(4)));

#define AS1 __attribute__((address_space(1)))
#define AS3 __attribute__((address_space(3)))

// ---------- helpers ----------

__device__ __forceinline__ u16 f2bf(float f) {
  u32 u = __float_as_uint(f);
  return (u16)((u + 0x7fffu + ((u >> 16) & 1u)) >> 16);
}

__device__ __forceinline__ void gload_lds16(const void* src, void* dst) {
  // 16B per lane, HW dest = wave-uniform base + lane*16
  __builtin_amdgcn_global_load_lds((const AS1 void*)src, (AS3 void*)dst, 16, 0, 0);
}

// linear fragment read from a [rows][128B] LDS tile
__device__ __forceinline__ bf16x8 fragL(const char* lds, int row, int kbyte) {
  return *(const bf16x8*)(lds + row * 128 + kbyte);
}

// ---------- fp32 -> bf16 conversion ----------

__global__ __launch_bounds__(256) void cvt_all(
    const float* q, const float* k, const float* v,
    const float* wq, const float* wk, const float* wv, const float* wo,
    u16* qb, u16* kb, u16* vb,
    u16* wqb, u16* wkb, u16* wvb, u16* wob)
{
  const float* src; u16* dst; int n4;
  switch (blockIdx.y) {
    case 0: src = q;  dst = qb;  n4 = 1048576; break;
    case 1: src = k;  dst = kb;  n4 = 1048576; break;
    case 2: src = v;  dst = vb;  n4 = 1048576; break;
    case 3: src = wq; dst = wqb; n4 = 262144;  break;
    case 4: src = wk; dst = wkb; n4 = 262144;  break;
    case 5: src = wv; dst = wvb; n4 = 262144;  break;
    default: src = wo; dst = wob; n4 = 262144; break;
  }
  int stride = gridDim.x * blockDim.x;
  for (int i = blockIdx.x * blockDim.x + threadIdx.x; i < n4; i += stride) {
    float4 f = ((const float4*)src)[i];
    ushort4 o;
    o.x = f2bf(f.x); o.y = f2bf(f.y); o.z = f2bf(f.z); o.w = f2bf(f.w);
    ((ushort4*)dst)[i] = o;
  }
}

// ---------- GEMM core: C[128x128] = A[128xK] * W[128xK]^T, K=1024 ----------
// m97-exact: linear LDS [128 rows][64 k] bf16 (128B rows), linear
// global_load_lds staging, linear ds_read_b128 fragments.

__device__ __forceinline__ void stageL(const u16* gtile, char* lds, int tid)
{
  int w = tid >> 6, lane = tid & 63;
  int rr = lane >> 3;               // row within 8-row chunk
  int cb = (lane & 7) << 4;         // byte col within 128B row
  #pragma unroll
  for (int i = 0; i < 4; ++i) {
    int c = i * 4 + w;              // chunk 0..15, 1KB each (8 rows)
    gload_lds16((const char*)(gtile + (c * 8 + rr) * 1024) + cb, lds + c * 1024);
  }
}

__device__ __forceinline__ void gemm_core(const u16* A, const u16* W,
                                          f32x4 acc[4][4], int bi, int bj,
                                          int tid, char* As, char* Bs)
{
  int lane = tid & 63;
  int wr = (tid >> 7) & 1, wc = (tid >> 6) & 1;
  for (int kt = 0; kt < 16; ++kt) {
    stageL(A + bi * 128 * 1024 + kt * 64, As, tid);
    stageL(W + bj * 128 * 1024 + kt * 64, Bs, tid);
    __syncthreads();
    #pragma unroll
    for (int ks = 0; ks < 2; ++ks) {
      int kb = ks * 64 + ((lane >> 4) << 4);
      bf16x8 af[4], bfr[4];
      #pragma unroll
      for (int m = 0; m < 4; ++m) af[m]  = fragL(As, wr * 64 + m * 16 + (lane & 15), kb);
      #pragma unroll
      for (int n = 0; n < 4; ++n) bfr[n] = fragL(Bs, wc * 64 + n * 16 + (lane & 15), kb);
      #pragma unroll
      for (int m = 0; m < 4; ++m)
        #pragma unroll
        for (int n = 0; n < 4; ++n)
          acc[m][n] = __builtin_amdgcn_mfma_f32_16x16x32_bf16(af[m], bfr[n], acc[m][n], 0, 0, 0);
    }
    __syncthreads();
  }
}

// ---------- QKV projection (z=0:Q, 1:K, 2:V) ----------
// Q,K out: [B,H,T,D]  V out: [B,H,D,T] (transposed for attention PV)

__global__ __launch_bounds__(256, 2) void proj_gemm(
    const u16* qb, const u16* kb, const u16* vb,
    const u16* wqb, const u16* wkb, const u16* wvb,
    const float* bq, const float* bk, const float* bv,
    u16* qh, u16* kh, u16* vt)
{
  __shared__ alignas(16) char As[16384];
  __shared__ alignas(16) char Bs[16384];
  int tid = threadIdx.x;
  int bi = blockIdx.x & 31, bj = blockIdx.x >> 5;
  int z = blockIdx.z;
  const u16* A = (z == 0) ? qb : (z == 1) ? kb : vb;
  const u16* W = (z == 0) ? wqb : (z == 1) ? wkb : wvb;
  const float* bias = (z == 0) ? bq : (z == 1) ? bk : bv;
  u16* dst = (z == 0) ? qh : (z == 1) ? kh : vt;

  f32x4 acc[4][4] = {};
  gemm_core(A, W, acc, bi, bj, tid, As, Bs);

  int lane = tid & 63, wr = (tid >> 7) & 1, wc = (tid >> 6) & 1;
  int rbase = bi * 128 + wr * 64 + ((lane >> 4) << 2);
  int cbase = bj * 128 + wc * 64;
  #pragma unroll
  for (int n = 0; n < 4; ++n) {
    int col = cbase + n * 16 + (lane & 15);
    float bsv = bias[col];
    int h = col >> 6, d = col & 63;
    #pragma unroll
    for (int m = 0; m < 4; ++m) {
      #pragma unroll
      for (int r = 0; r < 4; ++r) {
        int R = rbase + m * 16 + r;
        int b = R >> 10, t = R & 1023;
        u16 val = f2bf(acc[m][n][r] + bsv);
        if (z < 2) dst[(((b * 16 + h) * 1024 + t) << 6) + d] = val;
        else       dst[(((b * 16 + h) * 64 + d) << 10) + t] = val;
      }
    }
  }
}

// ---------- output projection: attn[4096x1024] @ Wo^T + bo -> FP32 d_out ----

__global__ __launch_bounds__(256, 2) void out_gemm(
    const u16* attn, const u16* wob, const float* bo, float* out)
{
  __shared__ alignas(16) char As[16384];
  __shared__ alignas(16) char Bs[16384];
  int tid = threadIdx.x;
  int bi = blockIdx.x & 31, bj = blockIdx.x >> 5;

  f32x4 acc[4][4] = {};
  gemm_core(attn, wob, acc, bi, bj, tid, As, Bs);

  int lane = tid & 63, wr = (tid >> 7) & 1, wc = (tid >> 6) & 1;
  int rbase = bi * 128 + wr * 64 + ((lane >> 4) << 2);
  int cbase = bj * 128 + wc * 64;
  #pragma unroll
  for (int n = 0; n < 4; ++n) {
    int col = cbase + n * 16 + (lane & 15);
    float bsv = bo[col];
    #pragma unroll
    for (int m = 0; m < 4; ++m) {
      #pragma unroll
      for (int r = 0; r < 4; ++r) {
        int R = rbase + m * 16 + r;
        out[R * 1024 + col] = acc[m][n][r] + bsv;   // fp32 output
      }
    }
  }
}

// ---------- flash attention ----------
// grid (16, 64): x = q-tile (64 rows), y = b*16+h. 4 waves x 16 q-rows.
// Swapped QK^T: S^T = mfma(K, Q). PV: O^T = mfma(V^T, P^T).
// K and V^T staged via plain reg loads -> padded LDS [64][72].

__global__ __launch_bounds__(256, 2) void attn_fwd(
    const u16* qh, const u16* kh, const u16* vt, u16* attnb)
{
  __shared__ alignas(16) u16 Ks[64 * 72];
  __shared__ alignas(16) u16 Vs[64 * 72];
  __shared__ alignas(16) u16 Pl[4][16 * 72];

  int tid = threadIdx.x, lane = tid & 63, w = tid >> 6;
  int g = lane >> 4;
  int q0 = blockIdx.x << 6;
  int bh = blockIdx.y;
  const u16* qbase = qh + bh * 65536;   // [t][d]
  const u16* kbase = kh + bh * 65536;   // [t][d]
  const u16* vbase = vt + bh * 65536;   // [d][t]

  // Q fragment (B-operand): lane holds Q[q0+w*16+(lane&15)][g*8.. / 32+g*8..]
  bf16x8 qf[2];
  {
    int qrow = q0 + w * 16 + (lane & 15);
    const u16* p = qbase + qrow * 64 + (g << 3);
    qf[0] = *(const bf16x8*)p;
    qf[1] = *(const bf16x8*)(p + 32);
  }

  f32x4 ot[4] = {};
  float m_r = -3.0e38f, l_r = 0.f;

  int sr = tid >> 2;                 // staging row 0..63
  int sj = (tid & 3) << 4;           // staging col {0,16,32,48}
  u16* pw = Pl[w];
  int prow = (lane & 15) * 72;

  for (int kv0 = 0; kv0 < 1024; kv0 += 64) {
    // stage K[kv][d] and V^T[d][kv] tiles
    {
      const u16* ksrc = kbase + (kv0 + sr) * 64 + sj;
      const u16* vsrc = vbase + sr * 1024 + kv0 + sj;
      *(bf16x8*)(Ks + sr * 72 + sj)     = *(const bf16x8*)ksrc;
      *(bf16x8*)(Ks + sr * 72 + sj + 8) = *(const bf16x8*)(ksrc + 8);
      *(bf16x8*)(Vs + sr * 72 + sj)     = *(const bf16x8*)vsrc;
      *(bf16x8*)(Vs + sr * 72 + sj + 8) = *(const bf16x8*)(vsrc + 8);
    }
    __syncthreads();

    // S^T = K * Q^T
    f32x4 sc[4] = {};
    #pragma unroll
    for (int ks = 0; ks < 2; ++ks) {
      #pragma unroll
      for (int m = 0; m < 4; ++m) {
        bf16x8 kf = *(const bf16x8*)(Ks + (m * 16 + (lane & 15)) * 72 + ks * 32 + g * 8);
        sc[m] = __builtin_amdgcn_mfma_f32_16x16x32_bf16(kf, qf[ks], sc[m], 0, 0, 0);
      }
    }

    // online softmax (row q = lane&15; 4 lane-groups share a row)
    float sv[4][4];
    float vmax = -3.0e38f;
    #pragma unroll
    for (int m = 0; m < 4; ++m)
      #pragma unroll
      for (int r = 0; r < 4; ++r) {
        sv[m][r] = sc[m][r] * 0.125f;
        vmax = fmaxf(vmax, sv[m][r]);
      }
    vmax = fmaxf(vmax, __shfl_xor(vmax, 16, 64));
    vmax = fmaxf(vmax, __shfl_xor(vmax, 32, 64));
    float mnew = fmaxf(m_r, vmax);
    float fac = __expf(m_r - mnew);
    float psum = 0.f;
    u32 pp[4][2];
    #pragma unroll
    for (int m = 0; m < 4; ++m) {
      float p0 = __expf(sv[m][0] - mnew);
      float p1 = __expf(sv[m][1] - mnew);
      float p2 = __expf(sv[m][2] - mnew);
      float p3 = __expf(sv[m][3] - mnew);
      psum += (p0 + p1) + (p2 + p3);
      pp[m][0] = (u32)f2bf(p0) | ((u32)f2bf(p1) << 16);
      pp[m][1] = (u32)f2bf(p2) | ((u32)f2bf(p3) << 16);
    }
    psum += __shfl_xor(psum, 16, 64);
    psum += __shfl_xor(psum, 32, 64);
    l_r = l_r * fac + psum;
    m_r = mnew;
    #pragma unroll
    for (int dm = 0; dm < 4; ++dm) ot[dm] *= fac;

    // P -> per-wave LDS [16 q][72 kv] (bf16); lane writes kv = m*16+g*4..+3
    #pragma unroll
    for (int m = 0; m < 4; ++m) {
      u32* d = (u32*)(pw + prow + m * 16 + (g << 2));
      d[0] = pp[m][0];
      d[1] = pp[m][1];
    }

    // O^T += V^T * P^T
    #pragma unroll
    for (int ks = 0; ks < 2; ++ks) {
      bf16x8 pf = *(const bf16x8*)(pw + prow + ks * 32 + g * 8);
      #pragma unroll
      for (int dm = 0; dm < 4; ++dm) {
        bf16x8 vf = *(const bf16x8*)(Vs + (dm * 16 + (lane & 15)) * 72 + ks * 32 + g * 8);
        ot[dm] = __builtin_amdgcn_mfma_f32_16x16x32_bf16(vf, pf, ot[dm], 0, 0, 0);
      }
    }
    __syncthreads();
  }

  // normalize + write merged-head attn [4096][1024] bf16
  float inv = 1.0f / l_r;
  int b = bh >> 4, h = bh & 15;
  int tok = (b << 10) + q0 + w * 16 + (lane & 15);
  u16* obase = attnb + tok * 1024 + h * 64;
  #pragma unroll
  for (int dm = 0; dm < 4; ++dm) {
    int d0 = dm * 16 + (g << 2);
    u32 lo = (u32)f2bf(ot[dm][0] * inv) | ((u32)f2bf(ot[dm][1] * inv) << 16);
    u32 hi = (u32)f2bf(ot[dm][2] * inv) | ((u32)f2bf(ot[dm][3] * inv) << 16);
    u32* d = (u32*)(obase + d0);
    d[0] = lo; d[1] = hi;
  }
}

// ---------- launch ----------

extern "C" void kernel_launch(void* const* d_in, const int* in_sizes, int n_in,
                              void* d_out, int out_size, void* d_ws, size_t ws_size,
                              hipStream_t stream)
{
  const float* q  = (const float*)d_in[0];
  const float* k  = (const float*)d_in[1];
  const float* v  = (const float*)d_in[2];
  const float* Wq = (const float*)d_in[3];
  const float* bq = (const float*)d_in[4];
  const float* Wk = (const float*)d_in[5];
  const float* bk = (const float*)d_in[6];
  const float* Wv = (const float*)d_in[7];
  const float* bv = (const float*)d_in[8];
  const float* Wo = (const float*)d_in[9];
  const float* bo = (const float*)d_in[10];
  float* out = (float*)d_out;          // reference output dtype = float32

  u16* ws  = (u16*)d_ws;
  u16* qb  = ws;                    // 4M elems each (bf16)
  u16* kb  = qb  + (4u << 20);
  u16* vb  = kb  + (4u << 20);
  u16* wqb = vb  + (4u << 20);      // 1M each
  u16* wkb = wqb + (1u << 20);
  u16* wvb = wkb + (1u << 20);
  u16* wob = wvb + (1u << 20);
  u16* qhb = wob + (1u << 20);      // 4M each
  u16* khb = qhb + (4u << 20);
  u16* vtb = khb + (4u << 20);
  u16* atb = vtb + (4u << 20);      // total 64 MiB

  cvt_all<<<dim3(1024, 7, 1), 256, 0, stream>>>(q, k, v, Wq, Wk, Wv, Wo,
                                                qb, kb, vb, wqb, wkb, wvb, wob);
  proj_gemm<<<dim3(256, 1, 3), 256, 0, stream>>>(qb, kb, vb, wqb, wkb, wvb,
                                                 bq, bk, bv, qhb, khb, vtb);
  attn_fwd<<<dim3(16, 64, 1), 256, 0, stream>>>(qhb, khb, vtb, atb);
  out_gemm<<<dim3(256, 1, 1), 256, 0, stream>>>(atb, wob, bo, out);
}